// Round 5
// baseline (355.415 us; speedup 1.0000x reference)
//
#include <hip/hip_runtime.h>

#define T_DIM 1024
#define B_DIM 64
#define H_DIM 1024
#define OSPLIT 16      // o-reduction split for v = hidden@W (512 blocks, depth 64)

// native clang vector type -> __builtin_nontemporal_load accepts it
typedef float floatx4 __attribute__((ext_vector_type(4)));

// nontemporal float4 load (enc is a read-once 268 MB stream).
// R2/R3 A/B: nt = 355 us vs plain = 385 us -> keep nt.
__device__ __forceinline__ float4 ldnt4(const float* p) {
    floatx4 r = __builtin_nontemporal_load(reinterpret_cast<const floatx4*>(p));
    return make_float4(r.x, r.y, r.z, r.w);
}

// ---------------------------------------------------------------------------
// Kernel 1: v_part[os][b][h] = sum_{o in chunk} hidden[b][o] * W[o][h]
// (unchanged — control)
// ---------------------------------------------------------------------------
__global__ __launch_bounds__(256) void gemv_hw(const float* __restrict__ hidden,
                                               const float* __restrict__ W,
                                               float* __restrict__ v_part) {
    __shared__ float hid_s[32 * 64];               // 8 KB: [bi][o]
    const int tid  = threadIdx.x;                  // 0..255
    const int lane = tid & 63;
    const int wv   = tid >> 6;                     // 0..3
    const int h    = blockIdx.x * 64 + lane;
    const int b0   = blockIdx.y * 32;
    const int o0   = blockIdx.z * 64;

#pragma unroll
    for (int r = 0; r < 2; ++r) {
        const int i  = tid + 256 * r;
        const int bi = i >> 4;                     // 16 float4 per b-row
        const int o4 = i & 15;
        reinterpret_cast<float4*>(hid_s)[i] =
            reinterpret_cast<const float4*>(hidden + (size_t)(b0 + bi) * H_DIM + o0)[o4];
    }
    __syncthreads();

    float acc[8];
#pragma unroll
    for (int j = 0; j < 8; ++j) acc[j] = 0.f;

    const float* wcol = W + (size_t)o0 * H_DIM + h;
    const float* hrow = hid_s + (wv * 8) * 64;     // this wave's 8 b-rows
#pragma unroll 4
    for (int o = 0; o < 64; ++o) {
        const float w = wcol[(size_t)o * H_DIM];
#pragma unroll
        for (int j = 0; j < 8; ++j) acc[j] += hrow[j * 64 + o] * w;
    }

    float* vp = v_part + ((size_t)blockIdx.z * B_DIM + b0 + wv * 8) * H_DIM + h;
#pragma unroll
    for (int j = 0; j < 8; ++j) vp[(size_t)j * H_DIM] = acc[j];
}

// ---------------------------------------------------------------------------
// Kernel 1b: v[b][h] = sum_os v_part[os][b][h]. (unchanged — control)
// ---------------------------------------------------------------------------
__global__ __launch_bounds__(256) void reduce_v(const float* __restrict__ v_part,
                                                float* __restrict__ v) {
    const int i = blockIdx.x * 256 + threadIdx.x;  // float4 index into [B*H/4)
    float4 s = make_float4(0.f, 0.f, 0.f, 0.f);
#pragma unroll
    for (int os = 0; os < OSPLIT; ++os) {
        const float4 p = reinterpret_cast<const float4*>(
            v_part + (size_t)os * B_DIM * H_DIM)[i];
        s.x += p.x; s.y += p.y; s.z += p.z; s.w += p.w;
    }
    reinterpret_cast<float4*>(v)[i] = s;
}

// ---------------------------------------------------------------------------
// Kernel 2 REWRITE (R4): persistent linear-sweep energies.
// Theory: old grid (t-chunk, b) read 4 KB granules scattered at 256 KB
// stride across all 268 MB (chip-wide random at 4 KB) -> ~1.65 TB/s.
// The 6.5 TB/s harness fill sweeps LINEARLY. New layout:
//   512 blocks x 512 threads (8 waves). Block x: b-half h = x&1 (32 b's),
//   t-base = x>>1. Iter i<4: plane t = tbase + 256*i. The 512 resident
//   blocks cover a contiguous ~64 MB window sliding linearly through enc.
//   Wave w owns b = 32h + 4w + j (j<4); caches v[b] rows in 64 VGPRs
//   (loaded once — no LDS, no barrier, no per-block v restage).
//   Per plane: 2 row-pair batches of 8 nt dwordx4 loads, dot, shfl-reduce.
// ---------------------------------------------------------------------------
__global__ __launch_bounds__(512) void energies_lin(const float* __restrict__ enc,
                                                    const float* __restrict__ v,
                                                    float* __restrict__ energies) {
    const int tid  = threadIdx.x;
    const int lane = tid & 63;
    const int wv   = tid >> 6;                     // 0..7
    const int hf   = blockIdx.x & 1;               // which b-half
    const int tb   = blockIdx.x >> 1;              // 0..255
    const int b0   = 32 * hf + 4 * wv;             // wave's first b

    // cache v[b0..b0+3], chunk layout matches enc loads: chunk k -> (k*64+lane)
    float4 vk[4][4];
#pragma unroll
    for (int j = 0; j < 4; ++j)
#pragma unroll
        for (int k = 0; k < 4; ++k)
            vk[j][k] = *reinterpret_cast<const float4*>(
                v + (size_t)(b0 + j) * H_DIM + (k * 64 + lane) * 4);

#pragma unroll
    for (int i = 0; i < 4; ++i) {
        const int t = tb + 256 * i;
        float p[4];
#pragma unroll
        for (int jp = 0; jp < 2; ++jp) {           // two row-pairs
            float4 e[2][4];
#pragma unroll
            for (int j = 0; j < 2; ++j) {
                const float* rp = enc + ((size_t)t * B_DIM + b0 + 2 * jp + j) * H_DIM;
#pragma unroll
                for (int k = 0; k < 4; ++k) e[j][k] = ldnt4(rp + (k * 64 + lane) * 4);
            }
#pragma unroll
            for (int j = 0; j < 2; ++j) {
                float acc = 0.f;
#pragma unroll
                for (int k = 0; k < 4; ++k) {
                    const float4 ee = e[j][k];
                    const float4 vv = vk[2 * jp + j][k];
                    acc += ee.x * vv.x + ee.y * vv.y + ee.z * vv.z + ee.w * vv.w;
                }
                p[2 * jp + j] = acc;
            }
        }
#pragma unroll
        for (int j = 0; j < 4; ++j) {
#pragma unroll
            for (int off = 32; off >= 1; off >>= 1) p[j] += __shfl_down(p[j], off, 64);
            if (lane == 0) energies[(size_t)(b0 + j) * T_DIM + t] = p[j];
        }
    }
}

// ---------------------------------------------------------------------------
// Kernel 3: softmax over t per b. (unchanged — control)
// ---------------------------------------------------------------------------
__global__ __launch_bounds__(256) void softmax_k(const float* __restrict__ energies,
                                                 float* __restrict__ out) {
    __shared__ float red[4];
    const int b    = blockIdx.x;
    const int tid  = threadIdx.x;
    const int lane = tid & 63;
    const int wave = tid >> 6;

    float4 e = reinterpret_cast<const float4*>(energies + (size_t)b * T_DIM)[tid];

    float m = fmaxf(fmaxf(e.x, e.y), fmaxf(e.z, e.w));
#pragma unroll
    for (int off = 32; off >= 1; off >>= 1) m = fmaxf(m, __shfl_xor(m, off, 64));
    if (lane == 0) red[wave] = m;
    __syncthreads();
    m = fmaxf(fmaxf(red[0], red[1]), fmaxf(red[2], red[3]));

    e.x = __expf(e.x - m); e.y = __expf(e.y - m);
    e.z = __expf(e.z - m); e.w = __expf(e.w - m);
    float s = e.x + e.y + e.z + e.w;
#pragma unroll
    for (int off = 32; off >= 1; off >>= 1) s += __shfl_xor(s, off, 64);
    __syncthreads();
    if (lane == 0) red[wave] = s;
    __syncthreads();
    s = red[0] + red[1] + red[2] + red[3];

    const float inv = 1.0f / s;
    const float4 o4 = make_float4(e.x * inv, e.y * inv, e.z * inv, e.w * inv);
    reinterpret_cast<float4*>(out + (size_t)b * T_DIM)[tid] = o4;
}

// ---------------------------------------------------------------------------
extern "C" void kernel_launch(void* const* d_in, const int* in_sizes, int n_in,
                              void* d_out, int out_size, void* d_ws, size_t ws_size,
                              hipStream_t stream) {
    (void)in_sizes; (void)n_in; (void)out_size; (void)ws_size;
    const float* hidden = (const float*)d_in[0];   // [1,B,H]
    const float* enc    = (const float*)d_in[1];   // [T,B,H]
    const float* W      = (const float*)d_in[2];   // [H,H]
    // d_in[3] = bias: constant over t -> cancelled by softmax, unused.

    float* v_part   = (float*)d_ws;                                       // 4 MB
    float* v        = v_part + (size_t)OSPLIT * B_DIM * H_DIM;            // 256 KB
    float* energies = v + (size_t)B_DIM * H_DIM;                          // 256 KB
    float* out = (float*)d_out;

    gemv_hw    <<<dim3(H_DIM / 64, B_DIM / 32, OSPLIT), 256, 0, stream>>>(hidden, W, v_part);
    reduce_v   <<<dim3(B_DIM * H_DIM / 4 / 256),        256, 0, stream>>>(v_part, v);
    energies_lin<<<dim3(512),                           512, 0, stream>>>(enc, v, energies);
    softmax_k  <<<dim3(B_DIM),                          256, 0, stream>>>(energies, out);
}